// Round 3
// baseline (778.341 us; speedup 1.0000x reference)
//
#include <hip/hip_runtime.h>
#include <math.h>

#define B   32
#define S   2048
#define D   512
#define H   512
#define G4  2048   // 4*H
#define NP  8
#define KC  8      // concat-K (1024) / 128
#define NCH 32     // S / SCHUNK
#define SCHUNK 64

__device__ __forceinline__ float sigmoidf_(float x) {
  return 1.0f / (1.0f + __expf(-x));
}

// ---------------- init: broadcast states, normalize num_sent dtype, zero counters ----------------
__global__ void k_init(const float* __restrict__ init_h, const float* __restrict__ init_c,
                       const float* __restrict__ init_in, const int* __restrict__ ns_raw,
                       float* __restrict__ h, float* __restrict__ c, float* __restrict__ xin,
                       int* __restrict__ ns, int* __restrict__ cnt) {
  int idx = blockIdx.x * blockDim.x + threadIdx.x;
  if (idx < B * H) {
    int d = idx & (H - 1);
    h[idx]   = init_h[d];
    c[idx]   = init_c[d];
    xin[idx] = init_in[d];
  }
  if (idx < NP * (1 + B)) cnt[idx] = 0;  // [0..7] gates counters; [8 + t*32 + b] attn counters
  if (idx == 0) {
    // num_sent >= 1 always. If int64 (LE), high word of elem 0 (raw[1]) is 0.
    bool is64 = (ns_raw[1] == 0);
    for (int i = 0; i < B; ++i) ns[i] = is64 ? ns_raw[2 * i] : ns_raw[i];
  }
}

// ---------------- fused: split-K gates GEMM + (tail blocks) hc + q ----------------
// grid (32, 9) x 256. kc<8: gates partial blocks. kc==8: 32 tail blocks (one per batch)
// that spin on a device counter, then combine partials -> h,c -> q = h@Wq.
// Co-residency: 288 blocks, 51.6 KB LDS -> 3 blocks/CU -> capacity 768 >= 288.
// Producers never wait => no deadlock even if residency assumption broke.
__global__ __launch_bounds__(256)
void k_gates_hcq(const float* __restrict__ W_ih, const float* __restrict__ W_hh,
                 const float* __restrict__ xin, const float* __restrict__ b_ih,
                 const float* __restrict__ b_hh, const float* __restrict__ Wq,
                 float* __restrict__ part, float* __restrict__ hbuf,
                 float* __restrict__ cbuf, float* __restrict__ qbuf,
                 int* __restrict__ cnt) {
  __shared__ float Ws[64][129];
  __shared__ float Xs[32][129];
  __shared__ float hs[512];
  const int kc = blockIdx.y;

  if (kc < 8) {
    // ---- gates partial GEMM: gates[b][j] = sum_k Xcat[b][k]*Wcat[j][k] ----
    const int j0 = blockIdx.x * 64;
    const bool second = (kc >= 4);
    const float* Wsrc = second ? W_hh : W_ih;
    const float* Xsrc = second ? hbuf : xin;   // reads h(t-1)/xin(t-1); tail writes h(t) only after cnt==256
    const int kk0 = (kc & 3) * 128;

    for (int l = threadIdx.x; l < 64 * 128; l += 256) {
      int j = l >> 7, k = l & 127;
      Ws[j][k] = Wsrc[(size_t)(j0 + j) * 512 + kk0 + k];
    }
    for (int l = threadIdx.x; l < 32 * 128; l += 256) {
      int b = l >> 7, k = l & 127;
      Xs[b][k] = Xsrc[b * 512 + kk0 + k];
    }
    __syncthreads();

    const int jj = (threadIdx.x & 31) * 2;   // 0..62
    const int bb = (threadIdx.x >> 5) * 4;   // 0..28
    float a00=0,a01=0,a02=0,a03=0,a10=0,a11=0,a12=0,a13=0;
    #pragma unroll 4
    for (int k = 0; k < 128; ++k) {
      float w0 = Ws[jj][k], w1 = Ws[jj + 1][k];
      float x0 = Xs[bb][k], x1 = Xs[bb+1][k], x2 = Xs[bb+2][k], x3 = Xs[bb+3][k];
      a00 += w0*x0; a01 += w0*x1; a02 += w0*x2; a03 += w0*x3;
      a10 += w1*x0; a11 += w1*x1; a12 += w1*x2; a13 += w1*x3;
    }
    size_t base = ((size_t)kc * B) * G4 + j0 + jj;
    part[base + (size_t)(bb+0)*G4]     = a00;
    part[base + (size_t)(bb+1)*G4]     = a01;
    part[base + (size_t)(bb+2)*G4]     = a02;
    part[base + (size_t)(bb+3)*G4]     = a03;
    part[base + (size_t)(bb+0)*G4 + 1] = a10;
    part[base + (size_t)(bb+1)*G4 + 1] = a11;
    part[base + (size_t)(bb+2)*G4 + 1] = a12;
    part[base + (size_t)(bb+3)*G4 + 1] = a13;

    __syncthreads();  // all stores issued (L1 write-through; dirty lines sit in this XCD's L2)
    if (threadIdx.x == 0)
      __hip_atomic_fetch_add(cnt, 1, __ATOMIC_RELEASE, __HIP_MEMORY_SCOPE_AGENT);  // wbL2 + signal
  } else {
    // ---- tail: one block per batch ----
    const int b = blockIdx.x;
    if (threadIdx.x == 0) {
      while (__hip_atomic_load(cnt, __ATOMIC_ACQUIRE, __HIP_MEMORY_SCOPE_AGENT) < 256)
        __builtin_amdgcn_s_sleep(2);
    }
    __syncthreads();  // acquire by tid0 invalidated this CU's L1 + XCD L2

    #pragma unroll
    for (int half = 0; half < 2; ++half) {
      const int hid = threadIdx.x + half * 256;
      const int idx = b * 512 + hid;
      float g[4];
      #pragma unroll
      for (int gi = 0; gi < 4; ++gi) {
        int j = gi * 512 + hid;
        float s = b_ih[j] + b_hh[j];
        #pragma unroll
        for (int kcc = 0; kcc < KC; ++kcc)
          s += part[((size_t)kcc * B + b) * G4 + j];
        g[gi] = s;
      }
      float i_ = sigmoidf_(g[0]);
      float f_ = sigmoidf_(g[1]);
      float gg = tanhf(g[2]);
      float o_ = sigmoidf_(g[3]);
      float cn = f_ * cbuf[idx] + i_ * gg;
      cbuf[idx] = cn;
      float hv = o_ * tanhf(cn);
      hbuf[idx] = hv;
      hs[hid] = hv;
    }
    __syncthreads();

    float acc0 = 0.f, acc1 = 0.f;
    #pragma unroll 8
    for (int k = 0; k < 512; ++k) {
      float hk = hs[k];
      acc0 += hk * Wq[(size_t)k * 512 + threadIdx.x];
      acc1 += hk * Wq[(size_t)k * 512 + threadIdx.x + 256];
    }
    qbuf[b * 512 + threadIdx.x]       = acc0;
    qbuf[b * 512 + threadIdx.x + 256] = acc1;
  }
}

// ---------------- attn chunk (pairwise online softmax) + last-block-per-batch reduce ----------------
// grid (NCH, B), block 256 = 4 waves; wave handles row pairs (2 rows per iteration).
// Last block to finish for a batch combines chunks, writes xin + score.
__global__ __launch_bounds__(256)
void k_attn(const float* __restrict__ enc, const float* __restrict__ q_buf,
            const int* __restrict__ ns_buf, float* __restrict__ ch_m,
            float* __restrict__ ch_l, float* __restrict__ ch_o,
            const float* __restrict__ score_W, const float* __restrict__ score_b,
            float* __restrict__ xin, float* __restrict__ scores,
            int* __restrict__ cnt) {
  __shared__ float wm[4], wl[4];
  __shared__ float wo[4][512];
  __shared__ int last_flag;
  const int b = blockIdx.y;
  const int ch = blockIdx.x;
  const int s0 = ch * SCHUNK;
  const int ns = ns_buf[b];
  const int lane = threadIdx.x & 63;
  const int wv = threadIdx.x >> 6;

  const float4* qp = (const float4*)(q_buf + b * 512 + lane * 8);
  const float4 qa = qp[0], qb = qp[1];

  float m = -1e30f, l = 0.f;
  float o0=0,o1=0,o2=0,o3=0,o4=0,o5=0,o6=0,o7=0;

  const int send = min(s0 + SCHUNK, ns);
  for (int p = wv; ; p += 4) {
    const int r0 = s0 + 2 * p;
    if (r0 >= send) break;
    const int r1 = r0 + 1;
    const bool has1 = (r1 < send);
    const float4* e0 = (const float4*)(enc + ((size_t)b * S + r0) * 512 + lane * 8);
    const float4* e1 = (const float4*)(enc + ((size_t)b * S + (has1 ? r1 : r0)) * 512 + lane * 8);
    float4 a0 = e0[0], a1 = e0[1];
    float4 c0 = e1[0], c1 = e1[1];
    float d0 = qa.x*a0.x + qa.y*a0.y + qa.z*a0.z + qa.w*a0.w
             + qb.x*a1.x + qb.y*a1.y + qb.z*a1.z + qb.w*a1.w;
    float d1 = qa.x*c0.x + qa.y*c0.y + qa.z*c0.z + qa.w*c0.w
             + qb.x*c1.x + qb.y*c1.y + qb.z*c1.z + qb.w*c1.w;
    #pragma unroll
    for (int off = 32; off > 0; off >>= 1) {
      d0 += __shfl_xor(d0, off);
      d1 += __shfl_xor(d1, off);
    }
    if (!has1) d1 = -1e30f;            // wave-uniform
    float nm = fmaxf(m, fmaxf(d0, d1));
    float sc = __expf(m - nm);
    float w0 = __expf(d0 - nm);
    float w1 = __expf(d1 - nm);        // 0 when invalid
    l = l * sc + w0 + w1;
    o0 = o0*sc + w0*a0.x + w1*c0.x; o1 = o1*sc + w0*a0.y + w1*c0.y;
    o2 = o2*sc + w0*a0.z + w1*c0.z; o3 = o3*sc + w0*a0.w + w1*c0.w;
    o4 = o4*sc + w0*a1.x + w1*c1.x; o5 = o5*sc + w0*a1.y + w1*c1.y;
    o6 = o6*sc + w0*a1.z + w1*c1.z; o7 = o7*sc + w0*a1.w + w1*c1.w;
    m = nm;
  }
  if (lane == 0) { wm[wv] = m; wl[wv] = l; }
  float4* wop = (float4*)&wo[wv][lane * 8];
  wop[0] = make_float4(o0, o1, o2, o3);
  wop[1] = make_float4(o4, o5, o6, o7);
  __syncthreads();

  const float M = fmaxf(fmaxf(wm[0], wm[1]), fmaxf(wm[2], wm[3]));
  const float e0 = __expf(wm[0]-M), e1 = __expf(wm[1]-M),
              e2 = __expf(wm[2]-M), e3 = __expf(wm[3]-M);
  if (threadIdx.x == 0) {
    ch_m[b*NCH + ch] = M;
    ch_l[b*NCH + ch] = wl[0]*e0 + wl[1]*e1 + wl[2]*e2 + wl[3]*e3;
  }
  for (int d = threadIdx.x; d < 512; d += 256) {
    float v = wo[0][d]*e0 + wo[1][d]*e1 + wo[2][d]*e2 + wo[3][d]*e3;
    ch_o[((size_t)(b * NCH + ch)) * 512 + d] = v;
  }

  // ---- last-block-per-batch chunk combine ----
  __syncthreads();  // all global stores issued
  if (threadIdx.x == 0) {
    int old = __hip_atomic_fetch_add(&cnt[b], 1, __ATOMIC_ACQ_REL, __HIP_MEMORY_SCOPE_AGENT);
    last_flag = (old == NCH - 1);
  }
  __syncthreads();
  if (!last_flag) return;

  // winner: caches invalidated by tid0's acquire; combine 32 chunks
  const int d0 = threadIdx.x, d1 = threadIdx.x + 256;
  float Mg = -1e30f;
  #pragma unroll
  for (int c = 0; c < NCH; ++c) Mg = fmaxf(Mg, ch_m[b*NCH + c]);
  float L = 0.f, acc0 = 0.f, acc1 = 0.f;
  #pragma unroll
  for (int c = 0; c < NCH; ++c) {
    float w = __expf(ch_m[b*NCH + c] - Mg);
    L += ch_l[b*NCH + c] * w;
    acc0 += w * ch_o[((size_t)(b*NCH + c)) * 512 + d0];
    acc1 += w * ch_o[((size_t)(b*NCH + c)) * 512 + d1];
  }
  const float invL = 1.0f / L;
  const float v0 = acc0 * invL, v1 = acc1 * invL;
  xin[b * 512 + d0] = v0;
  xin[b * 512 + d1] = v1;

  float* red = &wo[0][0];  // reuse LDS (all threads past the sync above)
  red[threadIdx.x] = v0 * score_W[d0] + v1 * score_W[d1];
  __syncthreads();
  for (int st = 128; st > 0; st >>= 1) {
    if (threadIdx.x < st) red[threadIdx.x] += red[threadIdx.x + st];
    __syncthreads();
  }
  if (threadIdx.x == 0) scores[b] = red[0] + score_b[0];
}

extern "C" void kernel_launch(void* const* d_in, const int* in_sizes, int n_in,
                              void* d_out, int out_size, void* d_ws, size_t ws_size,
                              hipStream_t stream) {
  const float* enc     = (const float*)d_in[0];
  const int*   ns_raw  = (const int*)d_in[1];
  // d_in[2] = num_pred (8)
  const float* init_h  = (const float*)d_in[3];
  const float* init_c  = (const float*)d_in[4];
  const float* init_in = (const float*)d_in[5];
  const float* W_ih    = (const float*)d_in[6];
  const float* W_hh    = (const float*)d_in[7];
  const float* b_ih    = (const float*)d_in[8];
  const float* b_hh    = (const float*)d_in[9];
  const float* Wq      = (const float*)d_in[10];
  const float* score_W = (const float*)d_in[11];
  const float* score_b = (const float*)d_in[12];
  float* out = (float*)d_out;

  float* ws    = (float*)d_ws;
  float* xin   = ws;               // 16384
  float* hbuf  = ws + 16384;       // 16384
  float* cbuf  = ws + 32768;       // 16384
  float* qbuf  = ws + 49152;       // 16384
  float* part  = ws + 65536;       // KC*B*G4 = 524288
  float* ch_m  = ws + 589824;      // B*NCH = 1024
  float* ch_l  = ws + 590848;      // 1024
  float* ch_o  = ws + 591872;      // B*NCH*D = 524288
  int*   ns    = (int*)(ws + 1116160);  // 32 ints
  int*   cnt   = (int*)(ws + 1116192);  // 8 + 8*32 = 264 ints

  k_init<<<64, 256, 0, stream>>>(init_h, init_c, init_in, ns_raw, hbuf, cbuf, xin, ns, cnt);
  for (int t = 0; t < NP; ++t) {
    k_gates_hcq<<<dim3(32, 9), 256, 0, stream>>>(W_ih, W_hh, xin, b_ih, b_hh, Wq,
                                                 part, hbuf, cbuf, qbuf, cnt + t);
    k_attn<<<dim3(NCH, B), 256, 0, stream>>>(enc, qbuf, ns, ch_m, ch_l, ch_o,
                                             score_W, score_b, xin, out + t * B,
                                             cnt + 8 + t * 32);
  }
}

// Round 4
// 371.254 us; speedup vs baseline: 2.0965x; 2.0965x over previous
//
#include <hip/hip_runtime.h>
#include <math.h>

#define B   32
#define S   2048
#define D   512
#define H   512
#define G4  2048   // 4*H
#define NP  8
#define KC  8      // concat-K (1024) / 128
#define NCH 32     // S / SCHUNK
#define SCHUNK 64

__device__ __forceinline__ float sigmoidf_(float x) {
  return 1.0f / (1.0f + __expf(-x));
}

// ---------------- init: broadcast initial states, normalize num_sent dtype ----------------
__global__ void k_init(const float* __restrict__ init_h, const float* __restrict__ init_c,
                       const float* __restrict__ init_in, const int* __restrict__ ns_raw,
                       float* __restrict__ h, float* __restrict__ c, float* __restrict__ xin,
                       int* __restrict__ ns) {
  int idx = blockIdx.x * blockDim.x + threadIdx.x;
  if (idx < B * H) {
    int d = idx & (H - 1);
    h[idx]   = init_h[d];
    c[idx]   = init_c[d];
    xin[idx] = init_in[d];
  }
  if (idx == 0) {
    // num_sent >= 1 always. If int64 (LE), high word of elem 0 (raw[1]) is 0.
    bool is64 = (ns_raw[1] == 0);
    for (int i = 0; i < B; ++i) ns[i] = is64 ? ns_raw[2 * i] : ns_raw[i];
  }
}

// ---------------- LSTM gates: split-K partial GEMM ----------------
// gates[b][j] = sum_k Xcat[b][k] * Wcat[j][k],  Xcat = [xin | h], Wcat = [W_ih | W_hh]
// grid (32 j-blocks of 64, 8 k-chunks of 128), block 256
__global__ __launch_bounds__(256)
void k_gates(const float* __restrict__ W_ih, const float* __restrict__ W_hh,
             const float* __restrict__ xin, const float* __restrict__ hbuf,
             float* __restrict__ part) {
  __shared__ float Ws[64][129];
  __shared__ float Xs[32][129];
  const int j0 = blockIdx.x * 64;
  const int kc = blockIdx.y;
  const bool second = (kc >= 4);
  const float* Wsrc = second ? W_hh : W_ih;
  const float* Xsrc = second ? hbuf : xin;
  const int kk0 = (kc & 3) * 128;

  for (int l = threadIdx.x; l < 64 * 128; l += 256) {
    int j = l >> 7, k = l & 127;
    Ws[j][k] = Wsrc[(size_t)(j0 + j) * 512 + kk0 + k];
  }
  for (int l = threadIdx.x; l < 32 * 128; l += 256) {
    int b = l >> 7, k = l & 127;
    Xs[b][k] = Xsrc[b * 512 + kk0 + k];
  }
  __syncthreads();

  const int jj = (threadIdx.x & 31) * 2;   // 0..62
  const int bb = (threadIdx.x >> 5) * 4;   // 0..28
  float a00=0,a01=0,a02=0,a03=0,a10=0,a11=0,a12=0,a13=0;
  #pragma unroll 4
  for (int k = 0; k < 128; ++k) {
    float w0 = Ws[jj][k], w1 = Ws[jj + 1][k];
    float x0 = Xs[bb][k], x1 = Xs[bb+1][k], x2 = Xs[bb+2][k], x3 = Xs[bb+3][k];
    a00 += w0*x0; a01 += w0*x1; a02 += w0*x2; a03 += w0*x3;
    a10 += w1*x0; a11 += w1*x1; a12 += w1*x2; a13 += w1*x3;
  }
  size_t base = ((size_t)kc * B) * G4 + j0 + jj;
  part[base + (size_t)(bb+0)*G4]     = a00;
  part[base + (size_t)(bb+1)*G4]     = a01;
  part[base + (size_t)(bb+2)*G4]     = a02;
  part[base + (size_t)(bb+3)*G4]     = a03;
  part[base + (size_t)(bb+0)*G4 + 1] = a10;
  part[base + (size_t)(bb+1)*G4 + 1] = a11;
  part[base + (size_t)(bb+2)*G4 + 1] = a12;
  part[base + (size_t)(bb+3)*G4 + 1] = a13;
}

// ---------------- fused: combine partials -> (h,c) -> q = h @ Wq ----------------
// grid 32 blocks (one per batch) x 512 threads
__global__ __launch_bounds__(512)
void k_hcq(const float* __restrict__ part, const float* __restrict__ b_ih,
           const float* __restrict__ b_hh, const float* __restrict__ Wq,
           float* __restrict__ h, float* __restrict__ c, float* __restrict__ q) {
  __shared__ float hs[512];
  const int b = blockIdx.x;
  const int hid = threadIdx.x;
  const int idx = b * 512 + hid;

  float g[4];
  #pragma unroll
  for (int gi = 0; gi < 4; ++gi) {
    int j = gi * 512 + hid;
    float s = b_ih[j] + b_hh[j];
    #pragma unroll
    for (int kc = 0; kc < KC; ++kc)
      s += part[((size_t)kc * B + b) * G4 + j];
    g[gi] = s;
  }
  float i_ = sigmoidf_(g[0]);
  float f_ = sigmoidf_(g[1]);
  float gg = tanhf(g[2]);
  float o_ = sigmoidf_(g[3]);
  float cn = f_ * c[idx] + i_ * gg;
  c[idx] = cn;
  float hv = o_ * tanhf(cn);
  h[idx] = hv;
  hs[hid] = hv;
  __syncthreads();

  float acc = 0.f;
  #pragma unroll 16
  for (int k = 0; k < 512; ++k)
    acc += hs[k] * Wq[(size_t)k * 512 + hid];
  q[idx] = acc;
}

// ---------------- one-pass online-softmax attention over an S-chunk ----------------
// grid (NCH, B) = 1024 blocks, block 512 = 8 waves.
// Each wave: 4 row-PAIRS (rows s0+2*wv, +1, stride 16), 1-pair-deep prefetch:
// next pair's 4 float4 loads issue before current pair's dot/shuffle/exp chain.
__global__ __launch_bounds__(512)
void k_attn(const float* __restrict__ enc, const float* __restrict__ q_buf,
            const int* __restrict__ ns_buf, float* __restrict__ ch_m,
            float* __restrict__ ch_l, float* __restrict__ ch_o) {
  __shared__ float wm[8], wl[8];
  __shared__ float wo[8][512];
  const int b = blockIdx.y;
  const int ch = blockIdx.x;
  const int s0 = ch * SCHUNK;
  const int ns = ns_buf[b];
  const int lane = threadIdx.x & 63;
  const int wv = threadIdx.x >> 6;   // 0..7

  const float4* qp = (const float4*)(q_buf + b * 512 + lane * 8);
  const float4 qa = qp[0], qb = qp[1];

  float m = -1e30f, l = 0.f;
  float o0=0,o1=0,o2=0,o3=0,o4=0,o5=0,o6=0,o7=0;

  const int send = min(s0 + SCHUNK, ns);
  const size_t rowbase = (size_t)b * S;

  int r = s0 + 2 * wv;
  if (r < send) {
    bool has1 = (r + 1 < send);
    const float4* p0 = (const float4*)(enc + (rowbase + r) * 512 + lane * 8);
    const float4* p1 = (const float4*)(enc + (rowbase + (has1 ? r + 1 : r)) * 512 + lane * 8);
    float4 a0 = p0[0], a1 = p0[1];
    float4 c0 = p1[0], c1 = p1[1];
    while (true) {
      const int rn = r + 16;
      const bool hasn = (rn < send);
      float4 na0, na1, nc0, nc1;
      bool nhas1 = false;
      if (hasn) {
        nhas1 = (rn + 1 < send);
        const float4* f0 = (const float4*)(enc + (rowbase + rn) * 512 + lane * 8);
        const float4* f1 = (const float4*)(enc + (rowbase + (nhas1 ? rn + 1 : rn)) * 512 + lane * 8);
        na0 = f0[0]; na1 = f0[1]; nc0 = f1[0]; nc1 = f1[1];
      }
      float d0 = qa.x*a0.x + qa.y*a0.y + qa.z*a0.z + qa.w*a0.w
               + qb.x*a1.x + qb.y*a1.y + qb.z*a1.z + qb.w*a1.w;
      float d1 = qa.x*c0.x + qa.y*c0.y + qa.z*c0.z + qa.w*c0.w
               + qb.x*c1.x + qb.y*c1.y + qb.z*c1.z + qb.w*c1.w;
      #pragma unroll
      for (int off = 32; off > 0; off >>= 1) {
        d0 += __shfl_xor(d0, off);
        d1 += __shfl_xor(d1, off);
      }
      if (!has1) d1 = -1e30f;            // wave-uniform
      float nm = fmaxf(m, fmaxf(d0, d1));
      float sc = __expf(m - nm);
      float w0 = __expf(d0 - nm);
      float w1 = __expf(d1 - nm);        // 0 when pair's 2nd row invalid
      l = l * sc + w0 + w1;
      o0 = o0*sc + w0*a0.x + w1*c0.x; o1 = o1*sc + w0*a0.y + w1*c0.y;
      o2 = o2*sc + w0*a0.z + w1*c0.z; o3 = o3*sc + w0*a0.w + w1*c0.w;
      o4 = o4*sc + w0*a1.x + w1*c1.x; o5 = o5*sc + w0*a1.y + w1*c1.y;
      o6 = o6*sc + w0*a1.z + w1*c1.z; o7 = o7*sc + w0*a1.w + w1*c1.w;
      m = nm;
      if (!hasn) break;
      r = rn; has1 = nhas1;
      a0 = na0; a1 = na1; c0 = nc0; c1 = nc1;
    }
  }
  if (lane == 0) { wm[wv] = m; wl[wv] = l; }
  float4* wop = (float4*)&wo[wv][lane * 8];
  wop[0] = make_float4(o0, o1, o2, o3);
  wop[1] = make_float4(o4, o5, o6, o7);
  __syncthreads();

  // combine the 8 waves' partials
  const int d = threadIdx.x;  // 0..511
  float M = wm[0];
  #pragma unroll
  for (int w = 1; w < 8; ++w) M = fmaxf(M, wm[w]);
  float e[8];
  float L = 0.f;
  #pragma unroll
  for (int w = 0; w < 8; ++w) { e[w] = __expf(wm[w] - M); L += wl[w] * e[w]; }
  if (threadIdx.x == 0) {
    ch_m[b*NCH + ch] = M;
    ch_l[b*NCH + ch] = L;
  }
  float v = 0.f;
  #pragma unroll
  for (int w = 0; w < 8; ++w) v += wo[w][d] * e[w];
  ch_o[((size_t)(b * NCH + ch)) * 512 + d] = v;
}

// ---------------- combine chunks -> out vector, score; out feeds next LSTM input ----------------
// grid B blocks x 256
__global__ __launch_bounds__(256)
void k_reduce(const float* __restrict__ ch_m, const float* __restrict__ ch_l,
              const float* __restrict__ ch_o, const float* __restrict__ score_W,
              const float* __restrict__ score_b, float* __restrict__ xin,
              float* __restrict__ scores) {
  __shared__ float red[256];
  const int b = blockIdx.x;
  float M = -1e30f;
  #pragma unroll
  for (int ch = 0; ch < NCH; ++ch) M = fmaxf(M, ch_m[b*NCH + ch]);
  float e[NCH];
  float L = 0.f;
  #pragma unroll
  for (int ch = 0; ch < NCH; ++ch) {
    e[ch] = __expf(ch_m[b*NCH + ch] - M);
    L += ch_l[b*NCH + ch] * e[ch];
  }
  const float invL = 1.0f / L;
  float partial = 0.f;
  for (int d = threadIdx.x; d < 512; d += 256) {
    float v = 0.f;
    #pragma unroll
    for (int ch = 0; ch < NCH; ++ch)
      v += ch_o[((size_t)(b*NCH + ch)) * 512 + d] * e[ch];
    v *= invL;
    xin[b * 512 + d] = v;
    partial += v * score_W[d];
  }
  red[threadIdx.x] = partial;
  __syncthreads();
  for (int st = 128; st > 0; st >>= 1) {
    if (threadIdx.x < st) red[threadIdx.x] += red[threadIdx.x + st];
    __syncthreads();
  }
  if (threadIdx.x == 0) scores[b] = red[0] + score_b[0];
}

extern "C" void kernel_launch(void* const* d_in, const int* in_sizes, int n_in,
                              void* d_out, int out_size, void* d_ws, size_t ws_size,
                              hipStream_t stream) {
  const float* enc     = (const float*)d_in[0];
  const int*   ns_raw  = (const int*)d_in[1];
  // d_in[2] = num_pred (8)
  const float* init_h  = (const float*)d_in[3];
  const float* init_c  = (const float*)d_in[4];
  const float* init_in = (const float*)d_in[5];
  const float* W_ih    = (const float*)d_in[6];
  const float* W_hh    = (const float*)d_in[7];
  const float* b_ih    = (const float*)d_in[8];
  const float* b_hh    = (const float*)d_in[9];
  const float* Wq      = (const float*)d_in[10];
  const float* score_W = (const float*)d_in[11];
  const float* score_b = (const float*)d_in[12];
  float* out = (float*)d_out;

  float* ws    = (float*)d_ws;
  float* xin   = ws;               // 16384
  float* hbuf  = ws + 16384;       // 16384
  float* cbuf  = ws + 32768;       // 16384
  float* qbuf  = ws + 49152;       // 16384
  float* part  = ws + 65536;       // KC*B*G4 = 524288
  float* ch_m  = ws + 589824;      // B*NCH = 1024
  float* ch_l  = ws + 590848;      // 1024
  float* ch_o  = ws + 591872;      // B*NCH*D = 524288
  int*   ns    = (int*)(ws + 1116160); // 32 ints

  k_init<<<64, 256, 0, stream>>>(init_h, init_c, init_in, ns_raw, hbuf, cbuf, xin, ns);
  for (int t = 0; t < NP; ++t) {
    k_gates<<<dim3(32, 8), 256, 0, stream>>>(W_ih, W_hh, xin, hbuf, part);
    k_hcq<<<B, 512, 0, stream>>>(part, b_ih, b_hh, Wq, hbuf, cbuf, qbuf);
    k_attn<<<dim3(NCH, B), 512, 0, stream>>>(enc, qbuf, ns, ch_m, ch_l, ch_o);
    k_reduce<<<B, 256, 0, stream>>>(ch_m, ch_l, ch_o, score_W, score_b, xin, out + t * B);
  }
}